// Round 8
// baseline (200.640 us; speedup 1.0000x reference)
//
#include <hip/hip_runtime.h>
#include <hip/hip_bf16.h>

// Problem dims (fixed by reference)
#define B_    8
#define C_    512
#define HW_   1024     // H*W = 32*32
#define NG    32
#define GCH   16
#define EPSV  1e-6f

typedef __attribute__((ext_vector_type(8))) short short8;   // 8 bf16 (4 VGPRs)
typedef __attribute__((ext_vector_type(4))) short short4v;  // 4 bf16
typedef __attribute__((ext_vector_type(4))) float floatx4;  // MFMA C/D

static __device__ __forceinline__ short f2bs(float f) {
  return __builtin_bit_cast(short, __float2bfloat16(f));
}
static __device__ __forceinline__ short4v pack4(float a, float b, float c, float d) {
  return (short4v){f2bs(a), f2bs(b), f2bs(c), f2bs(d)};
}
#define MFMA(a, b, c) __builtin_amdgcn_mfma_f32_16x16x32_bf16((a), (b), (c), 0, 0, 0)

// async global->LDS, 16 B per lane (global_load_lds_dwordx4)
static __device__ __forceinline__ void glds16(const short* g, short* l) {
  __builtin_amdgcn_global_load_lds(
      (const __attribute__((address_space(1))) void*)g,
      (__attribute__((address_space(3))) void*)l, 16, 0, 0);
}

// ---------------------------------------------------------------------------
// fp32 -> bf16 cast for BOTH weight tensors in one launch.
// ---------------------------------------------------------------------------
__global__ __launch_bounds__(256) void cast2_f2b(
    const float* __restrict__ s1, short* __restrict__ d1,
    const float* __restrict__ s2, short* __restrict__ d2) {
  int i = blockIdx.x * 256 + threadIdx.x;
  const float* s; short* d; int j;
  if (i < 196608) { s = s1; d = d1; j = i; }
  else            { s = s2; d = d2; j = i - 196608; }
  float4 v = reinterpret_cast<const float4*>(s)[j];
  reinterpret_cast<short4v*>(d)[j] = pack4(v.x, v.y, v.z, v.w);
}

// ---------------------------------------------------------------------------
// Kernel 1a: GroupNorm stats.  One block per (b, group) -> {mean, rsig}.
// ---------------------------------------------------------------------------
__global__ __launch_bounds__(256) void gn_stats(
    const float* __restrict__ x, float2* __restrict__ stats) {
  int bg = blockIdx.x;
  const int n = GCH * HW_;       // 16384
  const float* xp = x + (size_t)bg * n;
  int t = threadIdx.x;

  float s = 0.f, ss = 0.f;
  for (int i = t; i < n / 4; i += 256) {   // i indexes float4s
    float4 v = *reinterpret_cast<const float4*>(xp + i * 4);
    s  += (v.x + v.y) + (v.z + v.w);
    ss += (v.x * v.x + v.y * v.y) + (v.z * v.z + v.w * v.w);
  }
  for (int o = 32; o > 0; o >>= 1) {
    s  += __shfl_down(s, o);
    ss += __shfl_down(ss, o);
  }
  __shared__ float rs_[4], rss_[4];
  int wid = t >> 6, lane = t & 63;
  if (lane == 0) { rs_[wid] = s; rss_[wid] = ss; }
  __syncthreads();
  if (t == 0) {
    float stot  = rs_[0] + rs_[1] + rs_[2] + rs_[3];
    float sstot = rss_[0] + rss_[1] + rss_[2] + rss_[3];
    float mean = stot / (float)n;
    float var  = sstot / (float)n - mean * mean;
    stats[bg] = make_float2(mean, rsqrtf(var + EPSV));
  }
}

// ---------------------------------------------------------------------------
// Kernel 1b: normalize + transpose -> ht[b][seq][ch] bf16.
// ---------------------------------------------------------------------------
__global__ __launch_bounds__(256) void gn_apply(
    const float* __restrict__ x, const float2* __restrict__ stats,
    const float* __restrict__ gamma, const float* __restrict__ beta,
    short* __restrict__ ht) {
  __shared__ float Ls[64 * 65];
  int s0 = blockIdx.x * 64, ch0 = blockIdx.y * 64, b = blockIdx.z;
  int t = threadIdx.x;

  for (int i = 0; i < 4; i++) {
    int lin = t + i * 256;           // 64 rows x 16 float4
    int r = lin >> 4, c4 = lin & 15;
    int ch = ch0 + r;
    float2 st = stats[b * NG + (ch >> 4)];
    float ga = gamma[ch] * st.y;     // fold rsig into gamma
    float be = beta[ch] - st.x * ga;
    float4 v = *reinterpret_cast<const float4*>(
        x + ((size_t)(b * C_ + ch)) * HW_ + s0 + c4 * 4);
    Ls[r * 65 + c4 * 4 + 0] = v.x * ga + be;
    Ls[r * 65 + c4 * 4 + 1] = v.y * ga + be;
    Ls[r * 65 + c4 * 4 + 2] = v.z * ga + be;
    Ls[r * 65 + c4 * 4 + 3] = v.w * ga + be;
  }
  __syncthreads();
  for (int i = 0; i < 4; i++) {
    int lin = t + i * 256;           // 64 seq x 16 short4
    int sq = lin >> 4, cq = lin & 15;
    float a0 = Ls[(cq * 4 + 0) * 65 + sq];
    float a1 = Ls[(cq * 4 + 1) * 65 + sq];
    float a2 = Ls[(cq * 4 + 2) * 65 + sq];
    float a3 = Ls[(cq * 4 + 3) * 65 + sq];
    *reinterpret_cast<short4v*>(
        ht + ((size_t)b * 1024 + s0 + sq) * 512 + ch0 + cq * 4) =
        pack4(a0, a1, a2, a3);
  }
}

// ---------------------------------------------------------------------------
// Kernel 2: QKV GEMM, m97 structure (unchanged from r6 -- proven).
// ---------------------------------------------------------------------------
__global__ __launch_bounds__(256) void gemm_qkv(
    const short* __restrict__ Wb, const short* __restrict__ ht,
    const float* __restrict__ bias,
    short* __restrict__ Qt, short* __restrict__ Kt, short* __restrict__ Vn) {
  __shared__ short As[2][4096];   // [buf][row*32 + k]  128 rows x 32 k
  __shared__ short Bs[2][4096];
  int bx = blockIdx.x, by = blockIdx.y, bb = blockIdx.z;
  int m0 = by * 128, n0 = bx * 128;
  int t = threadIdx.x;
  int w = t >> 6, lane = t & 63, n16 = lane & 15, quad = lane >> 4;
  int wm = (w >> 1) * 64, wn = (w & 1) * 64;

  const short* Wa = Wb + (size_t)(m0 + (t >> 2)) * 512 + (t & 3) * 8;
  const short* Xa = ht + (size_t)bb * 1024 * 512 +
                    (size_t)(n0 + (t >> 2)) * 512 + (t & 3) * 8;

#define STAGE(buf, kk)                                                \
  do {                                                                \
    glds16(Wa + (kk), &As[buf][t * 8]);                               \
    glds16(Wa + 64 * 512 + (kk), &As[buf][2048 + t * 8]);             \
    glds16(Xa + (kk), &Bs[buf][t * 8]);                               \
    glds16(Xa + 64 * 512 + (kk), &Bs[buf][2048 + t * 8]);             \
  } while (0)

  floatx4 acc[4][4];
  for (int i = 0; i < 4; i++)
    for (int j = 0; j < 4; j++) acc[i][j] = (floatx4){0.f, 0.f, 0.f, 0.f};

  STAGE(0, 0);
#pragma unroll 1
  for (int ks = 0; ks < 16; ks++) {
    int cur = ks & 1;
    __syncthreads();                       // drains staging + prior ds_reads
    if (ks < 15) STAGE(cur ^ 1, (ks + 1) * 32);
    short8 a[4], b[4];
    for (int im = 0; im < 4; im++)
      a[im] = *reinterpret_cast<const short8*>(
          &As[cur][(wm + im * 16 + n16) * 32 + quad * 8]);
    for (int in = 0; in < 4; in++)
      b[in] = *reinterpret_cast<const short8*>(
          &Bs[cur][(wn + in * 16 + n16) * 32 + quad * 8]);
    for (int im = 0; im < 4; im++)
      for (int in = 0; in < 4; in++)
        acc[im][in] = MFMA(a[im], b[in], acc[im][in]);
  }
#undef STAGE

  if (m0 < 1024) {                 // Q or K: transposed store [seq][d]
    const bool isQ = (m0 < 512);
    short* base = isQ ? Qt : Kt;
    const float sc = isQ ? 0.125f : 1.0f;   // fold 1/sqrt(64) into Q
    for (int im = 0; im < 4; im++) {
      int m = m0 + wm + im * 16 + quad * 4;
      int hh = (m >> 6) & 7, d0 = m & 63;
      float4 bi = *reinterpret_cast<const float4*>(&bias[m]);
      short* hb = base + (size_t)(bb * 8 + hh) * 1024 * 64 + d0;
      for (int in = 0; in < 4; in++) {
        int nn = n0 + wn + in * 16 + n16;
        *reinterpret_cast<short4v*>(hb + (size_t)nn * 64) =
            pack4((acc[im][in][0] + bi.x) * sc, (acc[im][in][1] + bi.y) * sc,
                  (acc[im][in][2] + bi.z) * sc, (acc[im][in][3] + bi.w) * sc);
      }
    }
  } else {                         // V: natural store [ch][seq]
    for (int im = 0; im < 4; im++) {
      int m = m0 + wm + im * 16 + quad * 4;
      float4 bi = *reinterpret_cast<const float4*>(&bias[m]);
      int ch = m - 1024;
      for (int in = 0; in < 4; in++) {
        int nn = n0 + wn + in * 16 + n16;
        short* vp = Vn + (size_t)(bb * 512 + ch) * 1024 + nn;
        vp[0]    = f2bs(acc[im][in][0] + bi.x);
        vp[1024] = f2bs(acc[im][in][1] + bi.y);
        vp[2048] = f2bs(acc[im][in][2] + bi.z);
        vp[3072] = f2bs(acc[im][in][3] + bi.w);
      }
    }
  }
}

// ---------------------------------------------------------------------------
// Kernel 3: barrier-free MFMA attention + split-K, occupancy-unblocked.
//   r7 post-mortem: split-K gave NO co-residency (occ 18% = 2 blocks/CU,
//   duration = 2 serial passes).  r2 (plain launch_bounds, VGPR 64, LDS 16KB)
//   DID reach 44%.  Removing all three blockers vs r7:
//   (a) plain __launch_bounds__(256) -- no min-waves hint;
//   (b) LDS 32->16 KB: drop the [kt&1] P dbuf.  Ps is per-wave private and
//       same-wave DS ops complete in order, so read-before-overwrite holds;
//   (c) body otherwise byte-identical (no extra per-wave state -- r1/r5 rule).
// ---------------------------------------------------------------------------
__global__ __launch_bounds__(256) void attn_mfma(
    const short* __restrict__ Qt, const short* __restrict__ Kt,
    const short* __restrict__ Vn, short* __restrict__ attnT,
    float* __restrict__ Opart, float* __restrict__ lpart, int ksplit) {
  __shared__ short Ps[4][2][1024];   // [wave][qt][16*64]  16 KB
  int nblk = gridDim.x;
  int blk0 = blockIdx.x;
  int blk = (blk0 & 7) * (nblk >> 3) + (blk0 >> 3);  // XCD k owns batch k
  int tile = blk / ksplit, split = blk % ksplit;
  int qb = tile & 7, h = (tile >> 3) & 7, b = tile >> 6;
  int t = threadIdx.x;
  int w = t >> 6, lane = t & 63, n16 = lane & 15, quad = lane >> 4;
  int q0 = qb * 128 + w * 32;

  const short* Qp = Qt + (size_t)(b * 8 + h) * 1024 * 64;
  const short* Kp = Kt + (size_t)(b * 8 + h) * 1024 * 64;
  const short* Vp = Vn + (size_t)(b * 512 + h * 64) * 1024;

  short8 qa[2][2];
  for (int qt = 0; qt < 2; qt++)
    for (int f = 0; f < 2; f++)
      qa[qt][f] = *reinterpret_cast<const short8*>(
          Qp + (size_t)(q0 + qt * 16 + n16) * 64 + f * 32 + quad * 8);

  floatx4 O[2][4];
  float l[2][4];
  for (int qt = 0; qt < 2; qt++)
    for (int i = 0; i < 4; i++) {
      O[qt][i] = (floatx4){0.f, 0.f, 0.f, 0.f};
      l[qt][i] = 0.f;
    }

#define LOADK(dst, ktv)                                                      \
  do {                                                                       \
    int k0_ = (ktv) * 64;                                                    \
    for (int nt_ = 0; nt_ < 4; nt_++)                                        \
      for (int f_ = 0; f_ < 2; f_++)                                         \
        dst[nt_][f_] = *reinterpret_cast<const short8*>(                     \
            Kp + (size_t)(k0_ + nt_ * 16 + n16) * 64 + f_ * 32 + quad * 8);  \
  } while (0)

#define BODY(kf, ktv)                                                        \
  do {                                                                       \
    int k0_ = (ktv) * 64;                                                    \
    floatx4 S0_[4], S1_[4];                                                  \
    for (int nt_ = 0; nt_ < 4; nt_++) {                                      \
      floatx4 sa_ = (floatx4){0.f, 0.f, 0.f, 0.f};                           \
      sa_ = MFMA(qa[0][0], kf[nt_][0], sa_);                                 \
      S0_[nt_] = MFMA(qa[0][1], kf[nt_][1], sa_);                            \
    }                                                                        \
    for (int nt_ = 0; nt_ < 4; nt_++) {                                      \
      floatx4 sa_ = (floatx4){0.f, 0.f, 0.f, 0.f};                           \
      sa_ = MFMA(qa[1][0], kf[nt_][0], sa_);                                 \
      S1_[nt_] = MFMA(qa[1][1], kf[nt_][1], sa_);                            \
    }                                                                        \
    /* V for this kt: issue now, consume after softmax (L2 lat hidden) */    \
    short8 v_[4][2];                                                         \
    for (int nd_ = 0; nd_ < 4; nd_++) {                                      \
      const short* vs_ =                                                     \
          Vp + (size_t)(nd_ * 16 + n16) * 1024 + k0_ + quad * 8;             \
      v_[nd_][0] = *reinterpret_cast<const short8*>(vs_);                    \
      v_[nd_][1] = *reinterpret_cast<const short8*>(vs_ + 32);               \
    }                                                                        \
    short* Pb_ = &Ps[w][0][0];                                               \
    int sub_ = n16 & 7, hi_ = n16 >> 3;                                      \
    for (int r_ = 0; r_ < 4; r_++) {                                         \
      int row_ = quad * 4 + r_;                                              \
      float p0_ = __expf(S0_[0][r_]);                                        \
      float p1_ = __expf(S0_[1][r_]);                                        \
      float p2_ = __expf(S0_[2][r_]);                                        \
      float p3_ = __expf(S0_[3][r_]);                                        \
      l[0][r_] += (p0_ + p1_) + (p2_ + p3_);                                 \
      Pb_[row_ * 64 + ((0 + hi_ + row_) & 7) * 8 + sub_] = f2bs(p0_);        \
      Pb_[row_ * 64 + ((2 + hi_ + row_) & 7) * 8 + sub_] = f2bs(p1_);        \
      Pb_[row_ * 64 + ((4 + hi_ + row_) & 7) * 8 + sub_] = f2bs(p2_);        \
      Pb_[row_ * 64 + ((6 + hi_ + row_) & 7) * 8 + sub_] = f2bs(p3_);        \
    }                                                                        \
    for (int r_ = 0; r_ < 4; r_++) {                                         \
      int row_ = quad * 4 + r_;                                              \
      float p0_ = __expf(S1_[0][r_]);                                        \
      float p1_ = __expf(S1_[1][r_]);                                        \
      float p2_ = __expf(S1_[2][r_]);                                        \
      float p3_ = __expf(S1_[3][r_]);                                        \
      l[1][r_] += (p0_ + p1_) + (p2_ + p3_);                                 \
      Pb_[1024 + row_ * 64 + ((0 + hi_ + row_) & 7) * 8 + sub_] = f2bs(p0_); \
      Pb_[1024 + row_ * 64 + ((2 + hi_ + row_) & 7) * 8 + sub_] = f2bs(p1_); \
      Pb_[1024 + row_ * 64 + ((4 + hi_ + row_) & 7) * 8 + sub_] = f2bs(p2_); \
      Pb_[1024 + row_ * 64 + ((6 + hi_ + row_) & 7) * 8 + sub_] = f2bs(p3_); \
    }                                                                        \
    short8 pa0_[2], pa1_[2];                                                 \
    for (int f_ = 0; f_ < 2; f_++) {                                         \
      pa0_[f_] = *reinterpret_cast<const short8*>(                           \
          Pb_ + n16 * 64 + ((quad + 4 * f_ + n16) & 7) * 8);                 \
      pa1_[f_] = *reinterpret_cast<const short8*>(                           \
          Pb_ + 1024 + n16 * 64 + ((quad + 4 * f_ + n16) & 7) * 8);          \
    }                                                                        \
    __builtin_amdgcn_s_setprio(1);                                           \
    for (int nd_ = 0; nd_ < 4; nd_++) {                                      \
      O[0][nd_] = MFMA(pa0_[0], v_[nd_][0], O[0][nd_]);                      \
      O[0][nd_] = MFMA(pa0_[1], v_[nd_][1], O[0][nd_]);                      \
      O[1][nd_] = MFMA(pa1_[0], v_[nd_][0], O[1][nd_]);                      \
      O[1][nd_] = MFMA(pa1_[1], v_[nd_][1], O[1][nd_]);                      \
    }                                                                        \
    __builtin_amdgcn_s_setprio(0);                                           \
  } while (0)

  int ktn = 16 / ksplit;
  int kt0 = split * ktn, ktend = kt0 + ktn;
  short8 kfA[4][2], kfB[4][2];
  LOADK(kfA, kt0);
#pragma unroll 1
  for (int kt = kt0; kt < ktend; kt += 2) {
    LOADK(kfB, kt + 1);
    BODY(kfA, kt);
    if (kt + 2 < ktend) LOADK(kfA, kt + 2);
    BODY(kfB, kt + 1);
  }
#undef LOADK
#undef BODY

  // reduce l across the 16-lane row group (all 16 lanes get the sum)
  for (int qt = 0; qt < 2; qt++)
    for (int r = 0; r < 4; r++) {
      float s = l[qt][r];
      s += __shfl_xor(s, 1);
      s += __shfl_xor(s, 2);
      s += __shfl_xor(s, 4);
      s += __shfl_xor(s, 8);
      l[qt][r] = s;
    }

  if (ksplit == 1) {
    // direct write (exact r6 epilogue)
    for (int qt = 0; qt < 2; qt++)
      for (int nd = 0; nd < 4; nd++)
        for (int r = 0; r < 4; r++) {
          int q = q0 + qt * 16 + quad * 4 + r;
          int ch = h * 64 + nd * 16 + n16;
          attnT[((size_t)b * 1024 + q) * 512 + ch] =
              f2bs(O[qt][nd][r] / l[qt][r]);
        }
  } else {
    // partial write: unnormalized O (fp32) + l per q row
    float* Ob = Opart + (size_t)blk * 8192;   // [128][64]
    float* lb = lpart + blk * 128;
    int ql0 = w * 32;
    for (int qt = 0; qt < 2; qt++)
      for (int r = 0; r < 4; r++)
        if (n16 == 0) lb[ql0 + qt * 16 + quad * 4 + r] = l[qt][r];
    for (int qt = 0; qt < 2; qt++)
      for (int nd = 0; nd < 4; nd++)
        for (int r = 0; r < 4; r++)
          Ob[(ql0 + qt * 16 + quad * 4 + r) * 64 + nd * 16 + n16] =
              O[qt][nd][r];
  }
}

// ---------------------------------------------------------------------------
// Kernel 3b: split-K reduce (ksplit==2 only): sum 2 partials, normalize,
// write attnT bf16.  512 blocks, XCD-aligned with the partial producers.
// ---------------------------------------------------------------------------
__global__ __launch_bounds__(256) void attn_reduce(
    const float* __restrict__ Opart, const float* __restrict__ lpart,
    short* __restrict__ attnT) {
  int j0 = blockIdx.x;
  int j = (j0 & 7) * 64 + (j0 >> 3);       // XCD k -> batch k
  int t = threadIdx.x;
  int b = j >> 6, h = (j >> 3) & 7, qb = j & 7;
  const float4* O0 = reinterpret_cast<const float4*>(
      Opart + (size_t)(j * 2) * 8192);     // partials are contiguous pairs
  const float* l0 = lpart + (j * 2) * 128;
  for (int i = 0; i < 8; i++) {
    int lin = i * 256 + t;                 // 0..2047 float4s of [128][64]
    int q = lin >> 4, d4 = lin & 15;
    float4 a = O0[lin];
    float4 c = O0[2048 + lin];
    float inv = 1.0f / (l0[q] + l0[128 + q]);
    *reinterpret_cast<short4v*>(
        attnT + ((size_t)(b * 1024 + qb * 128 + q)) * 512 + h * 64 + d4 * 4) =
        pack4((a.x + c.x) * inv, (a.y + c.y) * inv,
              (a.z + c.z) * inv, (a.w + c.w) * inv);
  }
}

// ---------------------------------------------------------------------------
// Kernel 4: projection GEMM + bias + residual, 64x64 tiles (r7, kept:
// non-attn dropped ~3.5 us).  1024 blocks = 4 blocks/CU.
// ---------------------------------------------------------------------------
__global__ __launch_bounds__(256) void gemm_out(
    const short* __restrict__ Wb, const short* __restrict__ Xt,
    const float* __restrict__ bias, const float* __restrict__ resid,
    float* __restrict__ out) {
  __shared__ short As[2][2048];   // 64 rows x 32 k
  __shared__ short Bs[2][2048];
  int bx = blockIdx.x, by = blockIdx.y, bb = blockIdx.z;
  int m0 = by * 64, n0 = bx * 64;
  int t = threadIdx.x;
  int w = t >> 6, lane = t & 63, n16 = lane & 15, quad = lane >> 4;
  int wm = (w >> 1) * 32, wn = (w & 1) * 32;

  const short* Wa = Wb + (size_t)(m0 + (t >> 2)) * 512 + (t & 3) * 8;
  const short* Xa = Xt + (size_t)bb * 1024 * 512 +
                    (size_t)(n0 + (t >> 2)) * 512 + (t & 3) * 8;

#define STAGE(buf, kk)                                                \
  do {                                                                \
    glds16(Wa + (kk), &As[buf][t * 8]);                               \
    glds16(Xa + (kk), &Bs[buf][t * 8]);                               \
  } while (0)

  floatx4 acc[2][2];
  for (int i = 0; i < 2; i++)
    for (int j = 0; j < 2; j++) acc[i][j] = (floatx4){0.f, 0.f, 0.f, 0.f};

  STAGE(0, 0);
#pragma unroll 1
  for (int ks = 0; ks < 16; ks++) {
    int cur = ks & 1;
    __syncthreads();
    if (ks < 15) STAGE(cur ^ 1, (ks + 1) * 32);
    short8 a[2], b[2];
    for (int im = 0; im < 2; im++)
      a[im] = *reinterpret_cast<const short8*>(
          &As[cur][(wm + im * 16 + n16) * 32 + quad * 8]);
    for (int in = 0; in < 2; in++)
      b[in] = *reinterpret_cast<const short8*>(
          &Bs[cur][(wn + in * 16 + n16) * 32 + quad * 8]);
    for (int im = 0; im < 2; im++)
      for (int in = 0; in < 2; in++)
        acc[im][in] = MFMA(a[im], b[in], acc[im][in]);
  }
#undef STAGE

  for (int im = 0; im < 2; im++) {
    int m = m0 + wm + im * 16 + quad * 4;
    float4 bi = *reinterpret_cast<const float4*>(&bias[m]);
    for (int in = 0; in < 2; in++) {
      int nn = n0 + wn + in * 16 + n16;
      size_t idx = ((size_t)bb * 512 + m) * 1024 + nn;
      out[idx]        = acc[im][in][0] + bi.x + resid[idx];
      out[idx + 1024] = acc[im][in][1] + bi.y + resid[idx + 1024];
      out[idx + 2048] = acc[im][in][2] + bi.z + resid[idx + 2048];
      out[idx + 3072] = acc[im][in][3] + bi.w + resid[idx + 3072];
    }
  }
}

// ---------------------------------------------------------------------------
extern "C" void kernel_launch(void* const* d_in, const int* in_sizes, int n_in,
                              void* d_out, int out_size, void* d_ws, size_t ws_size,
                              hipStream_t stream) {
  const float* x     = (const float*)d_in[0];
  const float* gamma = (const float*)d_in[1];
  const float* beta  = (const float*)d_in[2];
  const float* w_in  = (const float*)d_in[3];
  const float* b_in  = (const float*)d_in[4];
  const float* w_out = (const float*)d_in[5];
  const float* b_out = (const float*)d_in[6];
  float* out = (float*)d_out;

  char* ws = (char*)d_ws;
  short* ht    = (short*)ws;                    //  8 MiB [8][1024][512]
  short* Qt    = (short*)(ws + (8u  << 20));    //  8 MiB [64][1024][64]
  short* Kt    = (short*)(ws + (16u << 20));    //  8 MiB [64][1024][64]
  short* Vn    = (short*)(ws + (24u << 20));    //  8 MiB [8][512][1024]
  short* attnT = (short*)(ws + (32u << 20));    //  8 MiB [8][1024][512]
  short* wbf1  = (short*)(ws + (40u << 20));    //  1.5 MiB
  short* wbf2  = (short*)(ws + (42u << 20));    //  0.5 MiB
  float2* stats = (float2*)(ws + (44u << 20));  //  2 KiB [256]
  float* Opart = (float*)(ws + (46u << 20));    // 33.5 MiB [1024][128][64]
  float* lpart = (float*)(ws + (80u << 20));    //  0.5 MiB [1024][128]

  int ksplit = (ws_size >= ((size_t)81 << 20)) ? 2 : 1;

  cast2_f2b<<<1024, 256, 0, stream>>>(w_in, wbf1, w_out, wbf2);
  gn_stats<<<B_ * NG, 256, 0, stream>>>(x, stats);
  gn_apply<<<dim3(16, 8, B_), 256, 0, stream>>>(x, stats, gamma, beta, ht);
  gemm_qkv<<<dim3(8, 12, B_), 256, 0, stream>>>(wbf1, ht, b_in, Qt, Kt, Vn);
  attn_mfma<<<512 * ksplit, 256, 0, stream>>>(Qt, Kt, Vn, attnT, Opart, lpart,
                                              ksplit);
  if (ksplit == 2)
    attn_reduce<<<512, 256, 0, stream>>>(Opart, lpart, attnT);
  gemm_out<<<dim3(16, 8, B_), 256, 0, stream>>>(wbf2, attnT, b_out, x, out);
}

// Round 9
// 191.724 us; speedup vs baseline: 1.0465x; 1.0465x over previous
//
#include <hip/hip_runtime.h>
#include <hip/hip_bf16.h>

// Problem dims (fixed by reference)
#define B_    8
#define C_    512
#define HW_   1024     // H*W = 32*32
#define NG    32
#define GCH   16
#define EPSV  1e-6f

typedef __attribute__((ext_vector_type(8))) short short8;   // 8 bf16 (4 VGPRs)
typedef __attribute__((ext_vector_type(4))) short short4v;  // 4 bf16
typedef __attribute__((ext_vector_type(4))) float floatx4;  // MFMA C/D

static __device__ __forceinline__ short f2bs(float f) {
  return __builtin_bit_cast(short, __float2bfloat16(f));
}
static __device__ __forceinline__ short4v pack4(float a, float b, float c, float d) {
  return (short4v){f2bs(a), f2bs(b), f2bs(c), f2bs(d)};
}
static __device__ __forceinline__ unsigned pk2(float a, float b) {
  return (unsigned)(unsigned short)f2bs(a) |
         ((unsigned)(unsigned short)f2bs(b) << 16);
}
#define MFMA(a, b, c) __builtin_amdgcn_mfma_f32_16x16x32_bf16((a), (b), (c), 0, 0, 0)

// async global->LDS, 16 B per lane (global_load_lds_dwordx4)
static __device__ __forceinline__ void glds16(const short* g, short* l) {
  __builtin_amdgcn_global_load_lds(
      (const __attribute__((address_space(1))) void*)g,
      (__attribute__((address_space(3))) void*)l, 16, 0, 0);
}

// ---------------------------------------------------------------------------
// fp32 -> bf16 cast for BOTH weight tensors in one launch.
// ---------------------------------------------------------------------------
__global__ __launch_bounds__(256) void cast2_f2b(
    const float* __restrict__ s1, short* __restrict__ d1,
    const float* __restrict__ s2, short* __restrict__ d2) {
  int i = blockIdx.x * 256 + threadIdx.x;
  const float* s; short* d; int j;
  if (i < 196608) { s = s1; d = d1; j = i; }
  else            { s = s2; d = d2; j = i - 196608; }
  float4 v = reinterpret_cast<const float4*>(s)[j];
  reinterpret_cast<short4v*>(d)[j] = pack4(v.x, v.y, v.z, v.w);
}

// ---------------------------------------------------------------------------
// Kernel 1a: GroupNorm stats.  One block per (b, group) -> {mean, rsig}.
// ---------------------------------------------------------------------------
__global__ __launch_bounds__(256) void gn_stats(
    const float* __restrict__ x, float2* __restrict__ stats) {
  int bg = blockIdx.x;
  const int n = GCH * HW_;       // 16384
  const float* xp = x + (size_t)bg * n;
  int t = threadIdx.x;

  float s = 0.f, ss = 0.f;
  for (int i = t; i < n / 4; i += 256) {   // i indexes float4s
    float4 v = *reinterpret_cast<const float4*>(xp + i * 4);
    s  += (v.x + v.y) + (v.z + v.w);
    ss += (v.x * v.x + v.y * v.y) + (v.z * v.z + v.w * v.w);
  }
  for (int o = 32; o > 0; o >>= 1) {
    s  += __shfl_down(s, o);
    ss += __shfl_down(ss, o);
  }
  __shared__ float rs_[4], rss_[4];
  int wid = t >> 6, lane = t & 63;
  if (lane == 0) { rs_[wid] = s; rss_[wid] = ss; }
  __syncthreads();
  if (t == 0) {
    float stot  = rs_[0] + rs_[1] + rs_[2] + rs_[3];
    float sstot = rss_[0] + rss_[1] + rss_[2] + rss_[3];
    float mean = stot / (float)n;
    float var  = sstot / (float)n - mean * mean;
    stats[bg] = make_float2(mean, rsqrtf(var + EPSV));
  }
}

// ---------------------------------------------------------------------------
// Kernel 1b: normalize + transpose -> ht[b][seq][ch] bf16.
// ---------------------------------------------------------------------------
__global__ __launch_bounds__(256) void gn_apply(
    const float* __restrict__ x, const float2* __restrict__ stats,
    const float* __restrict__ gamma, const float* __restrict__ beta,
    short* __restrict__ ht) {
  __shared__ float Ls[64 * 65];
  int s0 = blockIdx.x * 64, ch0 = blockIdx.y * 64, b = blockIdx.z;
  int t = threadIdx.x;

  for (int i = 0; i < 4; i++) {
    int lin = t + i * 256;           // 64 rows x 16 float4
    int r = lin >> 4, c4 = lin & 15;
    int ch = ch0 + r;
    float2 st = stats[b * NG + (ch >> 4)];
    float ga = gamma[ch] * st.y;     // fold rsig into gamma
    float be = beta[ch] - st.x * ga;
    float4 v = *reinterpret_cast<const float4*>(
        x + ((size_t)(b * C_ + ch)) * HW_ + s0 + c4 * 4);
    Ls[r * 65 + c4 * 4 + 0] = v.x * ga + be;
    Ls[r * 65 + c4 * 4 + 1] = v.y * ga + be;
    Ls[r * 65 + c4 * 4 + 2] = v.z * ga + be;
    Ls[r * 65 + c4 * 4 + 3] = v.w * ga + be;
  }
  __syncthreads();
  for (int i = 0; i < 4; i++) {
    int lin = t + i * 256;           // 64 seq x 16 short4
    int sq = lin >> 4, cq = lin & 15;
    float a0 = Ls[(cq * 4 + 0) * 65 + sq];
    float a1 = Ls[(cq * 4 + 1) * 65 + sq];
    float a2 = Ls[(cq * 4 + 2) * 65 + sq];
    float a3 = Ls[(cq * 4 + 3) * 65 + sq];
    *reinterpret_cast<short4v*>(
        ht + ((size_t)b * 1024 + s0 + sq) * 512 + ch0 + cq * 4) =
        pack4(a0, a1, a2, a3);
  }
}

// ---------------------------------------------------------------------------
// Kernel 2: QKV GEMM, m97 structure (unchanged from r6 -- proven).
// ---------------------------------------------------------------------------
__global__ __launch_bounds__(256) void gemm_qkv(
    const short* __restrict__ Wb, const short* __restrict__ ht,
    const float* __restrict__ bias,
    short* __restrict__ Qt, short* __restrict__ Kt, short* __restrict__ Vn) {
  __shared__ short As[2][4096];   // [buf][row*32 + k]  128 rows x 32 k
  __shared__ short Bs[2][4096];
  int bx = blockIdx.x, by = blockIdx.y, bb = blockIdx.z;
  int m0 = by * 128, n0 = bx * 128;
  int t = threadIdx.x;
  int w = t >> 6, lane = t & 63, n16 = lane & 15, quad = lane >> 4;
  int wm = (w >> 1) * 64, wn = (w & 1) * 64;

  const short* Wa = Wb + (size_t)(m0 + (t >> 2)) * 512 + (t & 3) * 8;
  const short* Xa = ht + (size_t)bb * 1024 * 512 +
                    (size_t)(n0 + (t >> 2)) * 512 + (t & 3) * 8;

#define STAGE(buf, kk)                                                \
  do {                                                                \
    glds16(Wa + (kk), &As[buf][t * 8]);                               \
    glds16(Wa + 64 * 512 + (kk), &As[buf][2048 + t * 8]);             \
    glds16(Xa + (kk), &Bs[buf][t * 8]);                               \
    glds16(Xa + 64 * 512 + (kk), &Bs[buf][2048 + t * 8]);             \
  } while (0)

  floatx4 acc[4][4];
  for (int i = 0; i < 4; i++)
    for (int j = 0; j < 4; j++) acc[i][j] = (floatx4){0.f, 0.f, 0.f, 0.f};

  STAGE(0, 0);
#pragma unroll 1
  for (int ks = 0; ks < 16; ks++) {
    int cur = ks & 1;
    __syncthreads();                       // drains staging + prior ds_reads
    if (ks < 15) STAGE(cur ^ 1, (ks + 1) * 32);
    short8 a[4], b[4];
    for (int im = 0; im < 4; im++)
      a[im] = *reinterpret_cast<const short8*>(
          &As[cur][(wm + im * 16 + n16) * 32 + quad * 8]);
    for (int in = 0; in < 4; in++)
      b[in] = *reinterpret_cast<const short8*>(
          &Bs[cur][(wn + in * 16 + n16) * 32 + quad * 8]);
    for (int im = 0; im < 4; im++)
      for (int in = 0; in < 4; in++)
        acc[im][in] = MFMA(a[im], b[in], acc[im][in]);
  }
#undef STAGE

  if (m0 < 1024) {                 // Q or K: transposed store [seq][d]
    const bool isQ = (m0 < 512);
    short* base = isQ ? Qt : Kt;
    const float sc = isQ ? 0.125f : 1.0f;   // fold 1/sqrt(64) into Q
    for (int im = 0; im < 4; im++) {
      int m = m0 + wm + im * 16 + quad * 4;
      int hh = (m >> 6) & 7, d0 = m & 63;
      float4 bi = *reinterpret_cast<const float4*>(&bias[m]);
      short* hb = base + (size_t)(bb * 8 + hh) * 1024 * 64 + d0;
      for (int in = 0; in < 4; in++) {
        int nn = n0 + wn + in * 16 + n16;
        *reinterpret_cast<short4v*>(hb + (size_t)nn * 64) =
            pack4((acc[im][in][0] + bi.x) * sc, (acc[im][in][1] + bi.y) * sc,
                  (acc[im][in][2] + bi.z) * sc, (acc[im][in][3] + bi.w) * sc);
      }
    }
  } else {                         // V: natural store [ch][seq]
    for (int im = 0; im < 4; im++) {
      int m = m0 + wm + im * 16 + quad * 4;
      float4 bi = *reinterpret_cast<const float4*>(&bias[m]);
      int ch = m - 1024;
      for (int in = 0; in < 4; in++) {
        int nn = n0 + wn + in * 16 + n16;
        short* vp = Vn + (size_t)(bb * 512 + ch) * 1024 + nn;
        vp[0]    = f2bs(acc[im][in][0] + bi.x);
        vp[1024] = f2bs(acc[im][in][1] + bi.y);
        vp[2048] = f2bs(acc[im][in][2] + bi.z);
        vp[3072] = f2bs(acc[im][in][3] + bi.w);
      }
    }
  }
}

// ---------------------------------------------------------------------------
// Kernel 3: attention v6 -- swapped QK^T + in-register softmax (NO LDS).
//   3 rounds proved occupancy doesn't convert to speed here; the cost is the
//   serial chain, dominated by P's LDS transit (32 ds_write -> lgkmcnt(0)
//   drain -> ds_read per qt per kt).  Swapped MFMA(K,Q) gives S^T with each
//   lane holding 16 k-values of ONE q-row (q=n16); after exp+bf16-pack, a
//   quad-level __shfl redistribution (srcA=(quad&1)*32+n16, srcB=srcA+16;
//   select by quad>>1) builds the PV A-fragment in registers.  P never
//   touches LDS.  l is lane-local; reduced via shfl_xor(16/32) at epilogue.
//   A/B fragments share one layout (row=lane&15, k=quad*8+j) so the operand
//   swap is free.  Grid 512, XCD remap kept, direct write, no split-K.
// ---------------------------------------------------------------------------
__global__ __launch_bounds__(256) void attn_mfma(
    const short* __restrict__ Qt, const short* __restrict__ Kt,
    const short* __restrict__ Vn, short* __restrict__ attnT) {
  int blk0 = blockIdx.x;
  int blk = (blk0 & 7) * 64 + (blk0 >> 3);   // 512 = 8 XCD x 64: batch->XCD
  int qb = blk & 7, h = (blk >> 3) & 7, b = blk >> 6;
  int t = threadIdx.x;
  int w = t >> 6, lane = t & 63, n16 = lane & 15, quad = lane >> 4;
  int q0 = qb * 128 + w * 32;
  int qhi = quad >> 1;
  int srcA = ((quad & 1) << 5) + n16;   // holder quad h0 = (2Q)&3
  int srcB = srcA + 16;                 // holder quad h1 = h0+1

  const short* Qp = Qt + (size_t)(b * 8 + h) * 1024 * 64;
  const short* Kp = Kt + (size_t)(b * 8 + h) * 1024 * 64;
  const short* Vp = Vn + (size_t)(b * 512 + h * 64) * 1024;

  short8 qa[2][2];
  for (int qt = 0; qt < 2; qt++)
    for (int f = 0; f < 2; f++)
      qa[qt][f] = *reinterpret_cast<const short8*>(
          Qp + (size_t)(q0 + qt * 16 + n16) * 64 + f * 32 + quad * 8);

  floatx4 O[2][4];
  float l[2] = {0.f, 0.f};
  for (int qt = 0; qt < 2; qt++)
    for (int i = 0; i < 4; i++) O[qt][i] = (floatx4){0.f, 0.f, 0.f, 0.f};

#define LOADK(dst, ktv)                                                      \
  do {                                                                       \
    int k0_ = (ktv) * 64;                                                    \
    for (int nt_ = 0; nt_ < 4; nt_++)                                        \
      for (int f_ = 0; f_ < 2; f_++)                                         \
        dst[nt_][f_] = *reinterpret_cast<const short8*>(                     \
            Kp + (size_t)(k0_ + nt_ * 16 + n16) * 64 + f_ * 32 + quad * 8);  \
  } while (0)

#define BODY(kf, ktv)                                                        \
  do {                                                                       \
    int k0_ = (ktv) * 64;                                                    \
    /* V for this kt: issue early, consume after softmax (L2 lat hidden) */  \
    short8 v_[4][2];                                                         \
    for (int nd_ = 0; nd_ < 4; nd_++) {                                      \
      const short* vs_ =                                                     \
          Vp + (size_t)(nd_ * 16 + n16) * 1024 + k0_ + quad * 8;             \
      v_[nd_][0] = *reinterpret_cast<const short8*>(vs_);                    \
      v_[nd_][1] = *reinterpret_cast<const short8*>(vs_ + 32);               \
    }                                                                        \
    _Pragma("unroll")                                                        \
    for (int qt_ = 0; qt_ < 2; qt_++) {                                      \
      /* swapped QK: T_[nt] lane -> S[q=n16][k=k0+nt*16+quad*4+r] */         \
      floatx4 T_[4];                                                         \
      _Pragma("unroll")                                                      \
      for (int nt_ = 0; nt_ < 4; nt_++) {                                    \
        floatx4 s_ = (floatx4){0.f, 0.f, 0.f, 0.f};                          \
        s_ = MFMA(kf[nt_][0], qa[qt_][0], s_);                               \
        T_[nt_] = MFMA(kf[nt_][1], qa[qt_][1], s_);                          \
      }                                                                      \
      unsigned u_[4][2];                                                     \
      _Pragma("unroll")                                                      \
      for (int nt_ = 0; nt_ < 4; nt_++) {                                    \
        float p0_ = __expf(T_[nt_][0]);                                      \
        float p1_ = __expf(T_[nt_][1]);                                      \
        float p2_ = __expf(T_[nt_][2]);                                      \
        float p3_ = __expf(T_[nt_][3]);                                      \
        l[qt_] += (p0_ + p1_) + (p2_ + p3_);                                 \
        u_[nt_][0] = pk2(p0_, p1_);                                         \
        u_[nt_][1] = pk2(p2_, p3_);                                         \
      }                                                                      \
      /* redistribute: pa_[f] j=0..7 <-> k=32f+8*quad+j */                   \
      short8 pa_[2];                                                         \
      _Pragma("unroll")                                                      \
      for (int f_ = 0; f_ < 2; f_++) {                                       \
        unsigned a0_ = (unsigned)__shfl((int)u_[2 * f_ + 0][0], srcA);       \
        unsigned a1_ = (unsigned)__shfl((int)u_[2 * f_ + 1][0], srcA);       \
        unsigned b0_ = (unsigned)__shfl((int)u_[2 * f_ + 0][1], srcA);       \
        unsigned b1_ = (unsigned)__shfl((int)u_[2 * f_ + 1][1], srcA);       \
        unsigned c0_ = (unsigned)__shfl((int)u_[2 * f_ + 0][0], srcB);       \
        unsigned c1_ = (unsigned)__shfl((int)u_[2 * f_ + 1][0], srcB);       \
        unsigned d0_ = (unsigned)__shfl((int)u_[2 * f_ + 0][1], srcB);       \
        unsigned d1_ = (unsigned)__shfl((int)u_[2 * f_ + 1][1], srcB);       \
        uint4 wv_;                                                           \
        wv_.x = qhi ? a1_ : a0_;                                             \
        wv_.y = qhi ? b1_ : b0_;                                             \
        wv_.z = qhi ? c1_ : c0_;                                             \
        wv_.w = qhi ? d1_ : d0_;                                             \
        pa_[f_] = __builtin_bit_cast(short8, wv_);                           \
      }                                                                      \
      __builtin_amdgcn_s_setprio(1);                                         \
      _Pragma("unroll")                                                      \
      for (int nd_ = 0; nd_ < 4; nd_++) {                                    \
        O[qt_][nd_] = MFMA(pa_[0], v_[nd_][0], O[qt_][nd_]);                 \
        O[qt_][nd_] = MFMA(pa_[1], v_[nd_][1], O[qt_][nd_]);                 \
      }                                                                      \
      __builtin_amdgcn_s_setprio(0);                                         \
    }                                                                        \
  } while (0)

  short8 kfA[4][2], kfB[4][2];
  LOADK(kfA, 0);
#pragma unroll 1
  for (int kt = 0; kt < 16; kt += 2) {
    LOADK(kfB, kt + 1);
    BODY(kfA, kt);
    if (kt + 2 < 16) LOADK(kfA, kt + 2);
    BODY(kfB, kt + 1);
  }
#undef LOADK
#undef BODY

  // epilogue: l is per-q (q=n16), spread over quads -> reduce over quads,
  // then each lane fetches l for its output rows q=quad*4+r via shfl.
  for (int qt = 0; qt < 2; qt++) {
    float s = l[qt];
    s += __shfl_xor(s, 16);
    s += __shfl_xor(s, 32);
    for (int nd = 0; nd < 4; nd++)
      for (int r = 0; r < 4; r++) {
        // fetched per r below; nd loop reuses it
        float linv = 1.0f / __shfl(s, quad * 4 + r);
        int q = q0 + qt * 16 + quad * 4 + r;
        int ch = h * 64 + nd * 16 + n16;
        attnT[((size_t)b * 1024 + q) * 512 + ch] = f2bs(O[qt][nd][r] * linv);
      }
  }
}

// ---------------------------------------------------------------------------
// Kernel 4: projection GEMM + bias + residual, 64x64 tiles (r7, kept).
// ---------------------------------------------------------------------------
__global__ __launch_bounds__(256) void gemm_out(
    const short* __restrict__ Wb, const short* __restrict__ Xt,
    const float* __restrict__ bias, const float* __restrict__ resid,
    float* __restrict__ out) {
  __shared__ short As[2][2048];   // 64 rows x 32 k
  __shared__ short Bs[2][2048];
  int bx = blockIdx.x, by = blockIdx.y, bb = blockIdx.z;
  int m0 = by * 64, n0 = bx * 64;
  int t = threadIdx.x;
  int w = t >> 6, lane = t & 63, n16 = lane & 15, quad = lane >> 4;
  int wm = (w >> 1) * 32, wn = (w & 1) * 32;

  const short* Wa = Wb + (size_t)(m0 + (t >> 2)) * 512 + (t & 3) * 8;
  const short* Xa = Xt + (size_t)bb * 1024 * 512 +
                    (size_t)(n0 + (t >> 2)) * 512 + (t & 3) * 8;

#define STAGE(buf, kk)                                                \
  do {                                                                \
    glds16(Wa + (kk), &As[buf][t * 8]);                               \
    glds16(Xa + (kk), &Bs[buf][t * 8]);                               \
  } while (0)

  floatx4 acc[2][2];
  for (int i = 0; i < 2; i++)
    for (int j = 0; j < 2; j++) acc[i][j] = (floatx4){0.f, 0.f, 0.f, 0.f};

  STAGE(0, 0);
#pragma unroll 1
  for (int ks = 0; ks < 16; ks++) {
    int cur = ks & 1;
    __syncthreads();
    if (ks < 15) STAGE(cur ^ 1, (ks + 1) * 32);
    short8 a[2], b[2];
    for (int im = 0; im < 2; im++)
      a[im] = *reinterpret_cast<const short8*>(
          &As[cur][(wm + im * 16 + n16) * 32 + quad * 8]);
    for (int in = 0; in < 2; in++)
      b[in] = *reinterpret_cast<const short8*>(
          &Bs[cur][(wn + in * 16 + n16) * 32 + quad * 8]);
    for (int im = 0; im < 2; im++)
      for (int in = 0; in < 2; in++)
        acc[im][in] = MFMA(a[im], b[in], acc[im][in]);
  }
#undef STAGE

  for (int im = 0; im < 2; im++) {
    int m = m0 + wm + im * 16 + quad * 4;
    float4 bi = *reinterpret_cast<const float4*>(&bias[m]);
    for (int in = 0; in < 2; in++) {
      int nn = n0 + wn + in * 16 + n16;
      size_t idx = ((size_t)bb * 512 + m) * 1024 + nn;
      out[idx]        = acc[im][in][0] + bi.x + resid[idx];
      out[idx + 1024] = acc[im][in][1] + bi.y + resid[idx + 1024];
      out[idx + 2048] = acc[im][in][2] + bi.z + resid[idx + 2048];
      out[idx + 3072] = acc[im][in][3] + bi.w + resid[idx + 3072];
    }
  }
}

// ---------------------------------------------------------------------------
extern "C" void kernel_launch(void* const* d_in, const int* in_sizes, int n_in,
                              void* d_out, int out_size, void* d_ws, size_t ws_size,
                              hipStream_t stream) {
  const float* x     = (const float*)d_in[0];
  const float* gamma = (const float*)d_in[1];
  const float* beta  = (const float*)d_in[2];
  const float* w_in  = (const float*)d_in[3];
  const float* b_in  = (const float*)d_in[4];
  const float* w_out = (const float*)d_in[5];
  const float* b_out = (const float*)d_in[6];
  float* out = (float*)d_out;

  char* ws = (char*)d_ws;
  short* ht    = (short*)ws;                    //  8 MiB [8][1024][512]
  short* Qt    = (short*)(ws + (8u  << 20));    //  8 MiB [64][1024][64]
  short* Kt    = (short*)(ws + (16u << 20));    //  8 MiB [64][1024][64]
  short* Vn    = (short*)(ws + (24u << 20));    //  8 MiB [8][512][1024]
  short* attnT = (short*)(ws + (32u << 20));    //  8 MiB [8][1024][512]
  short* wbf1  = (short*)(ws + (40u << 20));    //  1.5 MiB
  short* wbf2  = (short*)(ws + (42u << 20));    //  0.5 MiB
  float2* stats = (float2*)(ws + (44u << 20));  //  2 KiB [256]

  cast2_f2b<<<1024, 256, 0, stream>>>(w_in, wbf1, w_out, wbf2);
  gn_stats<<<B_ * NG, 256, 0, stream>>>(x, stats);
  gn_apply<<<dim3(16, 8, B_), 256, 0, stream>>>(x, stats, gamma, beta, ht);
  gemm_qkv<<<dim3(8, 12, B_), 256, 0, stream>>>(wbf1, ht, b_in, Qt, Kt, Vn);
  attn_mfma<<<512, 256, 0, stream>>>(Qt, Kt, Vn, attnT);
  gemm_out<<<dim3(16, 8, B_), 256, 0, stream>>>(wbf2, attnT, b_out, x, out);
}

// Round 10
// 190.250 us; speedup vs baseline: 1.0546x; 1.0077x over previous
//
#include <hip/hip_runtime.h>
#include <hip/hip_bf16.h>

// Problem dims (fixed by reference)
#define B_    8
#define C_    512
#define HW_   1024     // H*W = 32*32
#define NG    32
#define GCH   16
#define EPSV  1e-6f

typedef __attribute__((ext_vector_type(8))) short short8;   // 8 bf16 (4 VGPRs)
typedef __attribute__((ext_vector_type(4))) short short4v;  // 4 bf16
typedef __attribute__((ext_vector_type(4))) float floatx4;  // MFMA C/D

static __device__ __forceinline__ short f2bs(float f) {
  return __builtin_bit_cast(short, __float2bfloat16(f));
}
static __device__ __forceinline__ short4v pack4(float a, float b, float c, float d) {
  return (short4v){f2bs(a), f2bs(b), f2bs(c), f2bs(d)};
}
static __device__ __forceinline__ unsigned pk2(float a, float b) {
  return (unsigned)(unsigned short)f2bs(a) |
         ((unsigned)(unsigned short)f2bs(b) << 16);
}
#define MFMA(a, b, c) __builtin_amdgcn_mfma_f32_16x16x32_bf16((a), (b), (c), 0, 0, 0)

// async global->LDS, 16 B per lane (global_load_lds_dwordx4)
static __device__ __forceinline__ void glds16(const short* g, short* l) {
  __builtin_amdgcn_global_load_lds(
      (const __attribute__((address_space(1))) void*)g,
      (__attribute__((address_space(3))) void*)l, 16, 0, 0);
}

// ---------------------------------------------------------------------------
// fp32 -> bf16 cast for BOTH weight tensors in one launch.
// ---------------------------------------------------------------------------
__global__ __launch_bounds__(256) void cast2_f2b(
    const float* __restrict__ s1, short* __restrict__ d1,
    const float* __restrict__ s2, short* __restrict__ d2) {
  int i = blockIdx.x * 256 + threadIdx.x;
  const float* s; short* d; int j;
  if (i < 196608) { s = s1; d = d1; j = i; }
  else            { s = s2; d = d2; j = i - 196608; }
  float4 v = reinterpret_cast<const float4*>(s)[j];
  reinterpret_cast<short4v*>(d)[j] = pack4(v.x, v.y, v.z, v.w);
}

// ---------------------------------------------------------------------------
// Kernel 1a: GroupNorm stats.  One block per (b, group) -> {mean, rsig}.
// ---------------------------------------------------------------------------
__global__ __launch_bounds__(256) void gn_stats(
    const float* __restrict__ x, float2* __restrict__ stats) {
  int bg = blockIdx.x;
  const int n = GCH * HW_;       // 16384
  const float* xp = x + (size_t)bg * n;
  int t = threadIdx.x;

  float s = 0.f, ss = 0.f;
  for (int i = t; i < n / 4; i += 256) {   // i indexes float4s
    float4 v = *reinterpret_cast<const float4*>(xp + i * 4);
    s  += (v.x + v.y) + (v.z + v.w);
    ss += (v.x * v.x + v.y * v.y) + (v.z * v.z + v.w * v.w);
  }
  for (int o = 32; o > 0; o >>= 1) {
    s  += __shfl_down(s, o);
    ss += __shfl_down(ss, o);
  }
  __shared__ float rs_[4], rss_[4];
  int wid = t >> 6, lane = t & 63;
  if (lane == 0) { rs_[wid] = s; rss_[wid] = ss; }
  __syncthreads();
  if (t == 0) {
    float stot  = rs_[0] + rs_[1] + rs_[2] + rs_[3];
    float sstot = rss_[0] + rss_[1] + rss_[2] + rss_[3];
    float mean = stot / (float)n;
    float var  = sstot / (float)n - mean * mean;
    stats[bg] = make_float2(mean, rsqrtf(var + EPSV));
  }
}

// ---------------------------------------------------------------------------
// Kernel 1b: normalize + transpose -> ht[b][seq][ch] bf16.
// ---------------------------------------------------------------------------
__global__ __launch_bounds__(256) void gn_apply(
    const float* __restrict__ x, const float2* __restrict__ stats,
    const float* __restrict__ gamma, const float* __restrict__ beta,
    short* __restrict__ ht) {
  __shared__ float Ls[64 * 65];
  int s0 = blockIdx.x * 64, ch0 = blockIdx.y * 64, b = blockIdx.z;
  int t = threadIdx.x;

  for (int i = 0; i < 4; i++) {
    int lin = t + i * 256;           // 64 rows x 16 float4
    int r = lin >> 4, c4 = lin & 15;
    int ch = ch0 + r;
    float2 st = stats[b * NG + (ch >> 4)];
    float ga = gamma[ch] * st.y;     // fold rsig into gamma
    float be = beta[ch] - st.x * ga;
    float4 v = *reinterpret_cast<const float4*>(
        x + ((size_t)(b * C_ + ch)) * HW_ + s0 + c4 * 4);
    Ls[r * 65 + c4 * 4 + 0] = v.x * ga + be;
    Ls[r * 65 + c4 * 4 + 1] = v.y * ga + be;
    Ls[r * 65 + c4 * 4 + 2] = v.z * ga + be;
    Ls[r * 65 + c4 * 4 + 3] = v.w * ga + be;
  }
  __syncthreads();
  for (int i = 0; i < 4; i++) {
    int lin = t + i * 256;           // 64 seq x 16 short4
    int sq = lin >> 4, cq = lin & 15;
    float a0 = Ls[(cq * 4 + 0) * 65 + sq];
    float a1 = Ls[(cq * 4 + 1) * 65 + sq];
    float a2 = Ls[(cq * 4 + 2) * 65 + sq];
    float a3 = Ls[(cq * 4 + 3) * 65 + sq];
    *reinterpret_cast<short4v*>(
        ht + ((size_t)b * 1024 + s0 + sq) * 512 + ch0 + cq * 4) =
        pack4(a0, a1, a2, a3);
  }
}

// ---------------------------------------------------------------------------
// Kernel 2: QKV GEMM, m97 structure (unchanged from r6 -- proven).
// ---------------------------------------------------------------------------
__global__ __launch_bounds__(256) void gemm_qkv(
    const short* __restrict__ Wb, const short* __restrict__ ht,
    const float* __restrict__ bias,
    short* __restrict__ Qt, short* __restrict__ Kt, short* __restrict__ Vn) {
  __shared__ short As[2][4096];   // [buf][row*32 + k]  128 rows x 32 k
  __shared__ short Bs[2][4096];
  int bx = blockIdx.x, by = blockIdx.y, bb = blockIdx.z;
  int m0 = by * 128, n0 = bx * 128;
  int t = threadIdx.x;
  int w = t >> 6, lane = t & 63, n16 = lane & 15, quad = lane >> 4;
  int wm = (w >> 1) * 64, wn = (w & 1) * 64;

  const short* Wa = Wb + (size_t)(m0 + (t >> 2)) * 512 + (t & 3) * 8;
  const short* Xa = ht + (size_t)bb * 1024 * 512 +
                    (size_t)(n0 + (t >> 2)) * 512 + (t & 3) * 8;

#define STAGE(buf, kk)                                                \
  do {                                                                \
    glds16(Wa + (kk), &As[buf][t * 8]);                               \
    glds16(Wa + 64 * 512 + (kk), &As[buf][2048 + t * 8]);             \
    glds16(Xa + (kk), &Bs[buf][t * 8]);                               \
    glds16(Xa + 64 * 512 + (kk), &Bs[buf][2048 + t * 8]);             \
  } while (0)

  floatx4 acc[4][4];
  for (int i = 0; i < 4; i++)
    for (int j = 0; j < 4; j++) acc[i][j] = (floatx4){0.f, 0.f, 0.f, 0.f};

  STAGE(0, 0);
#pragma unroll 1
  for (int ks = 0; ks < 16; ks++) {
    int cur = ks & 1;
    __syncthreads();                       // drains staging + prior ds_reads
    if (ks < 15) STAGE(cur ^ 1, (ks + 1) * 32);
    short8 a[4], b[4];
    for (int im = 0; im < 4; im++)
      a[im] = *reinterpret_cast<const short8*>(
          &As[cur][(wm + im * 16 + n16) * 32 + quad * 8]);
    for (int in = 0; in < 4; in++)
      b[in] = *reinterpret_cast<const short8*>(
          &Bs[cur][(wn + in * 16 + n16) * 32 + quad * 8]);
    for (int im = 0; im < 4; im++)
      for (int in = 0; in < 4; in++)
        acc[im][in] = MFMA(a[im], b[in], acc[im][in]);
  }
#undef STAGE

  if (m0 < 1024) {                 // Q or K: transposed store [seq][d]
    const bool isQ = (m0 < 512);
    short* base = isQ ? Qt : Kt;
    const float sc = isQ ? 0.125f : 1.0f;   // fold 1/sqrt(64) into Q
    for (int im = 0; im < 4; im++) {
      int m = m0 + wm + im * 16 + quad * 4;
      int hh = (m >> 6) & 7, d0 = m & 63;
      float4 bi = *reinterpret_cast<const float4*>(&bias[m]);
      short* hb = base + (size_t)(bb * 8 + hh) * 1024 * 64 + d0;
      for (int in = 0; in < 4; in++) {
        int nn = n0 + wn + in * 16 + n16;
        *reinterpret_cast<short4v*>(hb + (size_t)nn * 64) =
            pack4((acc[im][in][0] + bi.x) * sc, (acc[im][in][1] + bi.y) * sc,
                  (acc[im][in][2] + bi.z) * sc, (acc[im][in][3] + bi.w) * sc);
      }
    }
  } else {                         // V: natural store [ch][seq]
    for (int im = 0; im < 4; im++) {
      int m = m0 + wm + im * 16 + quad * 4;
      float4 bi = *reinterpret_cast<const float4*>(&bias[m]);
      int ch = m - 1024;
      for (int in = 0; in < 4; in++) {
        int nn = n0 + wn + in * 16 + n16;
        short* vp = Vn + (size_t)(bb * 512 + ch) * 1024 + nn;
        vp[0]    = f2bs(acc[im][in][0] + bi.x);
        vp[1024] = f2bs(acc[im][in][1] + bi.y);
        vp[2048] = f2bs(acc[im][in][2] + bi.z);
        vp[3072] = f2bs(acc[im][in][3] + bi.w);
      }
    }
  }
}

// ---------------------------------------------------------------------------
// Kernel 3: attention v7 -- no-LDS swapped-QK body (r9, verified) +
// 2-tile rotation.  9 rounds showed per-block wall time = chain-traversals
// x ~10k cyc, invariant to occupancy/memory/LDS.  This halves traversals:
// tile-B's independent QK/softmax fills tile-A's stall windows:
//   QK-A | K-pf | V-A | SM-A | QK-B | K-pf | PV-A | V-B | SM-B | PV-B
// Every long-latency op has independent work after it in program order.
// amdgpu_waves_per_eu(2,2) pins the VGPR budget at 256 (r5's allocator
// squeezed to 128 under launch_bounds(256,2) and spilled; this forbids it).
// vA/vB never coexist (V-B issued after PV-A): peak ~200-220 VGPR.
// ---------------------------------------------------------------------------
__global__ __launch_bounds__(256)
__attribute__((amdgpu_waves_per_eu(2, 2))) void attn_mfma(
    const short* __restrict__ Qt, const short* __restrict__ Kt,
    const short* __restrict__ Vn, short* __restrict__ attnT) {
  int blk0 = blockIdx.x;
  int blk = (blk0 & 7) * 64 + (blk0 >> 3);   // 512 = 8 XCD x 64: batch->XCD
  int qb = blk & 7, h = (blk >> 3) & 7, b = blk >> 6;
  int t = threadIdx.x;
  int w = t >> 6, lane = t & 63, n16 = lane & 15, quad = lane >> 4;
  int q0 = qb * 128 + w * 32;
  int qhi = quad >> 1;
  int srcA = ((quad & 1) << 5) + n16;
  int srcB = srcA + 16;

  const short* Qp = Qt + (size_t)(b * 8 + h) * 1024 * 64;
  const short* Kp = Kt + (size_t)(b * 8 + h) * 1024 * 64;
  const short* Vp = Vn + (size_t)(b * 512 + h * 64) * 1024;

  short8 qa[2][2];
  for (int qt = 0; qt < 2; qt++)
    for (int f = 0; f < 2; f++)
      qa[qt][f] = *reinterpret_cast<const short8*>(
          Qp + (size_t)(q0 + qt * 16 + n16) * 64 + f * 32 + quad * 8);

  floatx4 O[2][4];
  float l[2] = {0.f, 0.f};
  for (int qt = 0; qt < 2; qt++)
    for (int i = 0; i < 4; i++) O[qt][i] = (floatx4){0.f, 0.f, 0.f, 0.f};

#define LOADK(dst, ktv)                                                      \
  do {                                                                       \
    int k0_ = (ktv) * 64;                                                    \
    for (int nt_ = 0; nt_ < 4; nt_++)                                        \
      for (int f_ = 0; f_ < 2; f_++)                                         \
        dst[nt_][f_] = *reinterpret_cast<const short8*>(                     \
            Kp + (size_t)(k0_ + nt_ * 16 + n16) * 64 + f_ * 32 + quad * 8);  \
  } while (0)

#define LOADV(dst, ktv)                                                      \
  do {                                                                       \
    int k0_ = (ktv) * 64;                                                    \
    for (int nd_ = 0; nd_ < 4; nd_++) {                                      \
      const short* vs_ =                                                     \
          Vp + (size_t)(nd_ * 16 + n16) * 1024 + k0_ + quad * 8;             \
      dst[nd_][0] = *reinterpret_cast<const short8*>(vs_);                   \
      dst[nd_][1] = *reinterpret_cast<const short8*>(vs_ + 32);              \
    }                                                                        \
  } while (0)

#define QKPH(kf, T)                                                          \
  do {                                                                       \
    _Pragma("unroll")                                                        \
    for (int qt_ = 0; qt_ < 2; qt_++) {                                      \
      _Pragma("unroll")                                                      \
      for (int nt_ = 0; nt_ < 4; nt_++) {                                    \
        floatx4 s_ = (floatx4){0.f, 0.f, 0.f, 0.f};                          \
        s_ = MFMA(kf[nt_][0], qa[qt_][0], s_);                               \
        T[qt_][nt_] = MFMA(kf[nt_][1], qa[qt_][1], s_);                      \
      }                                                                      \
    }                                                                        \
  } while (0)

#define SMAX(T, pa)                                                          \
  do {                                                                       \
    _Pragma("unroll")                                                        \
    for (int qt_ = 0; qt_ < 2; qt_++) {                                      \
      unsigned u_[4][2];                                                     \
      _Pragma("unroll")                                                      \
      for (int nt_ = 0; nt_ < 4; nt_++) {                                    \
        float p0_ = __expf(T[qt_][nt_][0]);                                  \
        float p1_ = __expf(T[qt_][nt_][1]);                                  \
        float p2_ = __expf(T[qt_][nt_][2]);                                  \
        float p3_ = __expf(T[qt_][nt_][3]);                                  \
        l[qt_] += (p0_ + p1_) + (p2_ + p3_);                                 \
        u_[nt_][0] = pk2(p0_, p1_);                                          \
        u_[nt_][1] = pk2(p2_, p3_);                                          \
      }                                                                      \
      _Pragma("unroll")                                                      \
      for (int f_ = 0; f_ < 2; f_++) {                                       \
        unsigned a0_ = (unsigned)__shfl((int)u_[2 * f_ + 0][0], srcA);       \
        unsigned a1_ = (unsigned)__shfl((int)u_[2 * f_ + 1][0], srcA);       \
        unsigned b0_ = (unsigned)__shfl((int)u_[2 * f_ + 0][1], srcA);       \
        unsigned b1_ = (unsigned)__shfl((int)u_[2 * f_ + 1][1], srcA);       \
        unsigned c0_ = (unsigned)__shfl((int)u_[2 * f_ + 0][0], srcB);       \
        unsigned c1_ = (unsigned)__shfl((int)u_[2 * f_ + 1][0], srcB);       \
        unsigned d0_ = (unsigned)__shfl((int)u_[2 * f_ + 0][1], srcB);       \
        unsigned d1_ = (unsigned)__shfl((int)u_[2 * f_ + 1][1], srcB);       \
        uint4 wv_;                                                           \
        wv_.x = qhi ? a1_ : a0_;                                             \
        wv_.y = qhi ? b1_ : b0_;                                             \
        wv_.z = qhi ? c1_ : c0_;                                             \
        wv_.w = qhi ? d1_ : d0_;                                             \
        pa[qt_][f_] = __builtin_bit_cast(short8, wv_);                       \
      }                                                                      \
    }                                                                        \
  } while (0)

#define PVPH(pa, v)                                                          \
  do {                                                                       \
    __builtin_amdgcn_s_setprio(1);                                           \
    _Pragma("unroll")                                                        \
    for (int qt_ = 0; qt_ < 2; qt_++) {                                      \
      _Pragma("unroll")                                                      \
      for (int nd_ = 0; nd_ < 4; nd_++) {                                    \
        O[qt_][nd_] = MFMA(pa[qt_][0], v[nd_][0], O[qt_][nd_]);              \
        O[qt_][nd_] = MFMA(pa[qt_][1], v[nd_][1], O[qt_][nd_]);              \
      }                                                                      \
    }                                                                        \
    __builtin_amdgcn_s_setprio(0);                                           \
  } while (0)

  short8 kfA[4][2], kfB[4][2];
  LOADK(kfA, 0);
  LOADK(kfB, 1);
#pragma unroll 1
  for (int kt = 0; kt < 16; kt += 2) {
    floatx4 TA[2][4], TB[2][4];
    short8 vA[4][2], vB[4][2], paA[2][2], paB[2][2];
    QKPH(kfA, TA);                       // kfA dead after this
    if (kt + 2 < 16) LOADK(kfA, kt + 2); // prefetch next pair (A)
    LOADV(vA, kt);                       // V-A in flight over SM-A + QK-B
    SMAX(TA, paA);                       // bpermute latency -> hidden by QK-B
    QKPH(kfB, TB);                       // independent MFMA work
    if (kt + 3 < 16) LOADK(kfB, kt + 3); // prefetch next pair (B)
    PVPH(paA, vA);                       // vA done long ago
    LOADV(vB, kt + 1);                   // V-B in flight over SM-B
    SMAX(TB, paB);
    PVPH(paB, vB);
  }
#undef LOADK
#undef LOADV
#undef QKPH
#undef SMAX
#undef PVPH

  // epilogue: l is per-q (q=n16), spread over quads -> reduce over quads,
  // then each lane fetches l for its output rows q=quad*4+r via shfl.
  for (int qt = 0; qt < 2; qt++) {
    float s = l[qt];
    s += __shfl_xor(s, 16);
    s += __shfl_xor(s, 32);
    for (int nd = 0; nd < 4; nd++)
      for (int r = 0; r < 4; r++) {
        float linv = 1.0f / __shfl(s, quad * 4 + r);
        int q = q0 + qt * 16 + quad * 4 + r;
        int ch = h * 64 + nd * 16 + n16;
        attnT[((size_t)b * 1024 + q) * 512 + ch] = f2bs(O[qt][nd][r] * linv);
      }
  }
}

// ---------------------------------------------------------------------------
// Kernel 4: projection GEMM + bias + residual, 64x64 tiles (r7, kept).
// ---------------------------------------------------------------------------
__global__ __launch_bounds__(256) void gemm_out(
    const short* __restrict__ Wb, const short* __restrict__ Xt,
    const float* __restrict__ bias, const float* __restrict__ resid,
    float* __restrict__ out) {
  __shared__ short As[2][2048];   // 64 rows x 32 k
  __shared__ short Bs[2][2048];
  int bx = blockIdx.x, by = blockIdx.y, bb = blockIdx.z;
  int m0 = by * 64, n0 = bx * 64;
  int t = threadIdx.x;
  int w = t >> 6, lane = t & 63, n16 = lane & 15, quad = lane >> 4;
  int wm = (w >> 1) * 32, wn = (w & 1) * 32;

  const short* Wa = Wb + (size_t)(m0 + (t >> 2)) * 512 + (t & 3) * 8;
  const short* Xa = Xt + (size_t)bb * 1024 * 512 +
                    (size_t)(n0 + (t >> 2)) * 512 + (t & 3) * 8;

#define STAGE(buf, kk)                                                \
  do {                                                                \
    glds16(Wa + (kk), &As[buf][t * 8]);                               \
    glds16(Xa + (kk), &Bs[buf][t * 8]);                               \
  } while (0)

  floatx4 acc[2][2];
  for (int i = 0; i < 2; i++)
    for (int j = 0; j < 2; j++) acc[i][j] = (floatx4){0.f, 0.f, 0.f, 0.f};

  STAGE(0, 0);
#pragma unroll 1
  for (int ks = 0; ks < 16; ks++) {
    int cur = ks & 1;
    __syncthreads();
    if (ks < 15) STAGE(cur ^ 1, (ks + 1) * 32);
    short8 a[2], b[2];
    for (int im = 0; im < 2; im++)
      a[im] = *reinterpret_cast<const short8*>(
          &As[cur][(wm + im * 16 + n16) * 32 + quad * 8]);
    for (int in = 0; in < 2; in++)
      b[in] = *reinterpret_cast<const short8*>(
          &Bs[cur][(wn + in * 16 + n16) * 32 + quad * 8]);
    for (int im = 0; im < 2; im++)
      for (int in = 0; in < 2; in++)
        acc[im][in] = MFMA(a[im], b[in], acc[im][in]);
  }
#undef STAGE

  for (int im = 0; im < 2; im++) {
    int m = m0 + wm + im * 16 + quad * 4;
    float4 bi = *reinterpret_cast<const float4*>(&bias[m]);
    for (int in = 0; in < 2; in++) {
      int nn = n0 + wn + in * 16 + n16;
      size_t idx = ((size_t)bb * 512 + m) * 1024 + nn;
      out[idx]        = acc[im][in][0] + bi.x + resid[idx];
      out[idx + 1024] = acc[im][in][1] + bi.y + resid[idx + 1024];
      out[idx + 2048] = acc[im][in][2] + bi.z + resid[idx + 2048];
      out[idx + 3072] = acc[im][in][3] + bi.w + resid[idx + 3072];
    }
  }
}

// ---------------------------------------------------------------------------
extern "C" void kernel_launch(void* const* d_in, const int* in_sizes, int n_in,
                              void* d_out, int out_size, void* d_ws, size_t ws_size,
                              hipStream_t stream) {
  const float* x     = (const float*)d_in[0];
  const float* gamma = (const float*)d_in[1];
  const float* beta  = (const float*)d_in[2];
  const float* w_in  = (const float*)d_in[3];
  const float* b_in  = (const float*)d_in[4];
  const float* w_out = (const float*)d_in[5];
  const float* b_out = (const float*)d_in[6];
  float* out = (float*)d_out;

  char* ws = (char*)d_ws;
  short* ht    = (short*)ws;                    //  8 MiB [8][1024][512]
  short* Qt    = (short*)(ws + (8u  << 20));    //  8 MiB [64][1024][64]
  short* Kt    = (short*)(ws + (16u << 20));    //  8 MiB [64][1024][64]
  short* Vn    = (short*)(ws + (24u << 20));    //  8 MiB [8][512][1024]
  short* attnT = (short*)(ws + (32u << 20));    //  8 MiB [8][1024][512]
  short* wbf1  = (short*)(ws + (40u << 20));    //  1.5 MiB
  short* wbf2  = (short*)(ws + (42u << 20));    //  0.5 MiB
  float2* stats = (float2*)(ws + (44u << 20));  //  2 KiB [256]

  cast2_f2b<<<1024, 256, 0, stream>>>(w_in, wbf1, w_out, wbf2);
  gn_stats<<<B_ * NG, 256, 0, stream>>>(x, stats);
  gn_apply<<<dim3(16, 8, B_), 256, 0, stream>>>(x, stats, gamma, beta, ht);
  gemm_qkv<<<dim3(8, 12, B_), 256, 0, stream>>>(wbf1, ht, b_in, Qt, Kt, Vn);
  attn_mfma<<<512, 256, 0, stream>>>(Qt, Kt, Vn, attnT);
  gemm_out<<<dim3(16, 8, B_), 256, 0, stream>>>(wbf2, attnT, b_out, x, out);
}

// Round 11
// 188.196 us; speedup vs baseline: 1.0661x; 1.0109x over previous
//
#include <hip/hip_runtime.h>
#include <hip/hip_bf16.h>

// Problem dims (fixed by reference)
#define B_    8
#define C_    512
#define HW_   1024     // H*W = 32*32
#define NG    32
#define GCH   16
#define EPSV  1e-6f

typedef __attribute__((ext_vector_type(8))) short short8;   // 8 bf16 (4 VGPRs)
typedef __attribute__((ext_vector_type(4))) short short4v;  // 4 bf16
typedef __attribute__((ext_vector_type(4))) float floatx4;  // MFMA C/D

static __device__ __forceinline__ short f2bs(float f) {
  return __builtin_bit_cast(short, __float2bfloat16(f));
}
static __device__ __forceinline__ short4v pack4(float a, float b, float c, float d) {
  return (short4v){f2bs(a), f2bs(b), f2bs(c), f2bs(d)};
}
static __device__ __forceinline__ unsigned pk2(float a, float b) {
  return (unsigned)(unsigned short)f2bs(a) |
         ((unsigned)(unsigned short)f2bs(b) << 16);
}
#define MFMA(a, b, c) __builtin_amdgcn_mfma_f32_16x16x32_bf16((a), (b), (c), 0, 0, 0)

// async global->LDS, 16 B per lane (global_load_lds_dwordx4)
static __device__ __forceinline__ void glds16(const short* g, short* l) {
  __builtin_amdgcn_global_load_lds(
      (const __attribute__((address_space(1))) void*)g,
      (__attribute__((address_space(3))) void*)l, 16, 0, 0);
}

// ---------------------------------------------------------------------------
// Kernel 1 (fused): GroupNorm stats+apply+transpose AND both weight casts.
//   Blocks 0..255   : one block per (b, group).  Phase 1 computes the group's
//     mean/rsig on-chip (no global stats round-trip).  Phase 2 re-reads the
//     group's 64 KB of x -- L2-hot (32 blocks/XCD x 64 KB = 2 MB < 4 MB) --
//     normalizes, transposes via LDS [16][65] subtiles, writes ht bf16.
//     x is read from HBM ONCE (was twice: gn_stats + gn_apply).
//   Blocks 256..1279: fp32->bf16 weight casts (was a separate launch).
//   6 launches -> 4 total.
// ---------------------------------------------------------------------------
__global__ __launch_bounds__(256) void gn_cast_fused(
    const float* __restrict__ x, const float* __restrict__ gamma,
    const float* __restrict__ beta, short* __restrict__ ht,
    const float* __restrict__ w_in, short* __restrict__ wbf1,
    const float* __restrict__ w_out, short* __restrict__ wbf2) {
  int blk = blockIdx.x;
  int t = threadIdx.x;

  if (blk >= 256) {                      // ---- weight cast blocks ----
    int i = (blk - 256) * 256 + t;       // 262144 float4s total
    const float* s; short* d; int j;
    if (i < 196608) { s = w_in; d = wbf1; j = i; }
    else            { s = w_out; d = wbf2; j = i - 196608; }
    float4 v = reinterpret_cast<const float4*>(s)[j];
    reinterpret_cast<short4v*>(d)[j] = pack4(v.x, v.y, v.z, v.w);
    return;
  }

  // ---- GroupNorm block: (b, g) ----
  int b = blk >> 5, g = blk & 31;
  const float* xp = x + ((size_t)(b * C_) + g * GCH) * HW_;  // 16 ch x 1024

  __shared__ float Ls[16 * 65];          // transpose subtile (4.2 KB)
  __shared__ float rs_[4], rss_[4], st_[2];

  // phase 1: stats over 16384 elements (16 f4 per thread, coalesced)
  float s = 0.f, ss = 0.f;
  for (int i = 0; i < 16; i++) {
    float4 v = *reinterpret_cast<const float4*>(xp + (t + i * 256) * 4);
    s  += (v.x + v.y) + (v.z + v.w);
    ss += (v.x * v.x + v.y * v.y) + (v.z * v.z + v.w * v.w);
  }
  for (int o = 32; o > 0; o >>= 1) {
    s  += __shfl_down(s, o);
    ss += __shfl_down(ss, o);
  }
  int wid = t >> 6, lane = t & 63;
  if (lane == 0) { rs_[wid] = s; rss_[wid] = ss; }
  __syncthreads();
  if (t == 0) {
    float stot  = rs_[0] + rs_[1] + rs_[2] + rs_[3];
    float sstot = rss_[0] + rss_[1] + rss_[2] + rss_[3];
    float mean = stot / 16384.f;
    float var  = sstot / 16384.f - mean * mean;
    st_[0] = mean;
    st_[1] = rsqrtf(var + EPSV);
  }
  __syncthreads();

  // per-thread channel (fixed across subtiles): r = t>>4 in [0,16)
  int r = t >> 4, c4 = t & 15;
  int ch = g * GCH + r;
  float ga = gamma[ch] * st_[1];
  float be = beta[ch] - st_[0] * ga;
  int sq = t >> 2, cq = t & 3;

  // phase 2: 16 seq-subtiles of 64; x re-read (L2-hot), transpose, write
  for (int stile = 0; stile < 16; stile++) {
    int s0 = stile * 64;
    float4 v = *reinterpret_cast<const float4*>(xp + r * HW_ + s0 + c4 * 4);
    Ls[r * 65 + c4 * 4 + 0] = v.x * ga + be;
    Ls[r * 65 + c4 * 4 + 1] = v.y * ga + be;
    Ls[r * 65 + c4 * 4 + 2] = v.z * ga + be;
    Ls[r * 65 + c4 * 4 + 3] = v.w * ga + be;
    __syncthreads();
    float a0 = Ls[(cq * 4 + 0) * 65 + sq];
    float a1 = Ls[(cq * 4 + 1) * 65 + sq];
    float a2 = Ls[(cq * 4 + 2) * 65 + sq];
    float a3 = Ls[(cq * 4 + 3) * 65 + sq];
    *reinterpret_cast<short4v*>(
        ht + ((size_t)b * 1024 + s0 + sq) * 512 + g * GCH + cq * 4) =
        pack4(a0, a1, a2, a3);
    __syncthreads();
  }
}

// ---------------------------------------------------------------------------
// Kernel 2: QKV GEMM, m97 structure (unchanged from r6 -- proven).
// ---------------------------------------------------------------------------
__global__ __launch_bounds__(256) void gemm_qkv(
    const short* __restrict__ Wb, const short* __restrict__ ht,
    const float* __restrict__ bias,
    short* __restrict__ Qt, short* __restrict__ Kt, short* __restrict__ Vn) {
  __shared__ short As[2][4096];   // [buf][row*32 + k]  128 rows x 32 k
  __shared__ short Bs[2][4096];
  int bx = blockIdx.x, by = blockIdx.y, bb = blockIdx.z;
  int m0 = by * 128, n0 = bx * 128;
  int t = threadIdx.x;
  int w = t >> 6, lane = t & 63, n16 = lane & 15, quad = lane >> 4;
  int wm = (w >> 1) * 64, wn = (w & 1) * 64;

  const short* Wa = Wb + (size_t)(m0 + (t >> 2)) * 512 + (t & 3) * 8;
  const short* Xa = ht + (size_t)bb * 1024 * 512 +
                    (size_t)(n0 + (t >> 2)) * 512 + (t & 3) * 8;

#define STAGE(buf, kk)                                                \
  do {                                                                \
    glds16(Wa + (kk), &As[buf][t * 8]);                               \
    glds16(Wa + 64 * 512 + (kk), &As[buf][2048 + t * 8]);             \
    glds16(Xa + (kk), &Bs[buf][t * 8]);                               \
    glds16(Xa + 64 * 512 + (kk), &Bs[buf][2048 + t * 8]);             \
  } while (0)

  floatx4 acc[4][4];
  for (int i = 0; i < 4; i++)
    for (int j = 0; j < 4; j++) acc[i][j] = (floatx4){0.f, 0.f, 0.f, 0.f};

  STAGE(0, 0);
#pragma unroll 1
  for (int ks = 0; ks < 16; ks++) {
    int cur = ks & 1;
    __syncthreads();                       // drains staging + prior ds_reads
    if (ks < 15) STAGE(cur ^ 1, (ks + 1) * 32);
    short8 a[4], b[4];
    for (int im = 0; im < 4; im++)
      a[im] = *reinterpret_cast<const short8*>(
          &As[cur][(wm + im * 16 + n16) * 32 + quad * 8]);
    for (int in = 0; in < 4; in++)
      b[in] = *reinterpret_cast<const short8*>(
          &Bs[cur][(wn + in * 16 + n16) * 32 + quad * 8]);
    for (int im = 0; im < 4; im++)
      for (int in = 0; in < 4; in++)
        acc[im][in] = MFMA(a[im], b[in], acc[im][in]);
  }
#undef STAGE

  if (m0 < 1024) {                 // Q or K: transposed store [seq][d]
    const bool isQ = (m0 < 512);
    short* base = isQ ? Qt : Kt;
    const float sc = isQ ? 0.125f : 1.0f;   // fold 1/sqrt(64) into Q
    for (int im = 0; im < 4; im++) {
      int m = m0 + wm + im * 16 + quad * 4;
      int hh = (m >> 6) & 7, d0 = m & 63;
      float4 bi = *reinterpret_cast<const float4*>(&bias[m]);
      short* hb = base + (size_t)(bb * 8 + hh) * 1024 * 64 + d0;
      for (int in = 0; in < 4; in++) {
        int nn = n0 + wn + in * 16 + n16;
        *reinterpret_cast<short4v*>(hb + (size_t)nn * 64) =
            pack4((acc[im][in][0] + bi.x) * sc, (acc[im][in][1] + bi.y) * sc,
                  (acc[im][in][2] + bi.z) * sc, (acc[im][in][3] + bi.w) * sc);
      }
    }
  } else {                         // V: natural store [ch][seq]
    for (int im = 0; im < 4; im++) {
      int m = m0 + wm + im * 16 + quad * 4;
      float4 bi = *reinterpret_cast<const float4*>(&bias[m]);
      int ch = m - 1024;
      for (int in = 0; in < 4; in++) {
        int nn = n0 + wn + in * 16 + n16;
        short* vp = Vn + (size_t)(bb * 512 + ch) * 1024 + nn;
        vp[0]    = f2bs(acc[im][in][0] + bi.x);
        vp[1024] = f2bs(acc[im][in][1] + bi.y);
        vp[2048] = f2bs(acc[im][in][2] + bi.z);
        vp[3072] = f2bs(acc[im][in][3] + bi.w);
      }
    }
  }
}

// ---------------------------------------------------------------------------
// Kernel 3: attention -- EXACT r9-benched body (67.3 us, VGPR 112, LDS 0).
// Swapped QK^T + in-register softmax; P never touches LDS.
// ---------------------------------------------------------------------------
__global__ __launch_bounds__(256) void attn_mfma(
    const short* __restrict__ Qt, const short* __restrict__ Kt,
    const short* __restrict__ Vn, short* __restrict__ attnT) {
  int blk0 = blockIdx.x;
  int blk = (blk0 & 7) * 64 + (blk0 >> 3);   // 512 = 8 XCD x 64: batch->XCD
  int qb = blk & 7, h = (blk >> 3) & 7, b = blk >> 6;
  int t = threadIdx.x;
  int w = t >> 6, lane = t & 63, n16 = lane & 15, quad = lane >> 4;
  int q0 = qb * 128 + w * 32;
  int qhi = quad >> 1;
  int srcA = ((quad & 1) << 5) + n16;
  int srcB = srcA + 16;

  const short* Qp = Qt + (size_t)(b * 8 + h) * 1024 * 64;
  const short* Kp = Kt + (size_t)(b * 8 + h) * 1024 * 64;
  const short* Vp = Vn + (size_t)(b * 512 + h * 64) * 1024;

  short8 qa[2][2];
  for (int qt = 0; qt < 2; qt++)
    for (int f = 0; f < 2; f++)
      qa[qt][f] = *reinterpret_cast<const short8*>(
          Qp + (size_t)(q0 + qt * 16 + n16) * 64 + f * 32 + quad * 8);

  floatx4 O[2][4];
  float l[2] = {0.f, 0.f};
  for (int qt = 0; qt < 2; qt++)
    for (int i = 0; i < 4; i++) O[qt][i] = (floatx4){0.f, 0.f, 0.f, 0.f};

#define LOADK(dst, ktv)                                                      \
  do {                                                                       \
    int k0_ = (ktv) * 64;                                                    \
    for (int nt_ = 0; nt_ < 4; nt_++)                                        \
      for (int f_ = 0; f_ < 2; f_++)                                         \
        dst[nt_][f_] = *reinterpret_cast<const short8*>(                     \
            Kp + (size_t)(k0_ + nt_ * 16 + n16) * 64 + f_ * 32 + quad * 8);  \
  } while (0)

#define BODY(kf, ktv)                                                        \
  do {                                                                       \
    int k0_ = (ktv) * 64;                                                    \
    short8 v_[4][2];                                                         \
    for (int nd_ = 0; nd_ < 4; nd_++) {                                      \
      const short* vs_ =                                                     \
          Vp + (size_t)(nd_ * 16 + n16) * 1024 + k0_ + quad * 8;             \
      v_[nd_][0] = *reinterpret_cast<const short8*>(vs_);                    \
      v_[nd_][1] = *reinterpret_cast<const short8*>(vs_ + 32);               \
    }                                                                        \
    _Pragma("unroll")                                                        \
    for (int qt_ = 0; qt_ < 2; qt_++) {                                      \
      floatx4 T_[4];                                                         \
      _Pragma("unroll")                                                      \
      for (int nt_ = 0; nt_ < 4; nt_++) {                                    \
        floatx4 s_ = (floatx4){0.f, 0.f, 0.f, 0.f};                          \
        s_ = MFMA(kf[nt_][0], qa[qt_][0], s_);                               \
        T_[nt_] = MFMA(kf[nt_][1], qa[qt_][1], s_);                          \
      }                                                                      \
      unsigned u_[4][2];                                                     \
      _Pragma("unroll")                                                      \
      for (int nt_ = 0; nt_ < 4; nt_++) {                                    \
        float p0_ = __expf(T_[nt_][0]);                                      \
        float p1_ = __expf(T_[nt_][1]);                                      \
        float p2_ = __expf(T_[nt_][2]);                                      \
        float p3_ = __expf(T_[nt_][3]);                                      \
        l[qt_] += (p0_ + p1_) + (p2_ + p3_);                                 \
        u_[nt_][0] = pk2(p0_, p1_);                                         \
        u_[nt_][1] = pk2(p2_, p3_);                                         \
      }                                                                      \
      short8 pa_[2];                                                         \
      _Pragma("unroll")                                                      \
      for (int f_ = 0; f_ < 2; f_++) {                                       \
        unsigned a0_ = (unsigned)__shfl((int)u_[2 * f_ + 0][0], srcA);       \
        unsigned a1_ = (unsigned)__shfl((int)u_[2 * f_ + 1][0], srcA);       \
        unsigned b0_ = (unsigned)__shfl((int)u_[2 * f_ + 0][1], srcA);       \
        unsigned b1_ = (unsigned)__shfl((int)u_[2 * f_ + 1][1], srcA);       \
        unsigned c0_ = (unsigned)__shfl((int)u_[2 * f_ + 0][0], srcB);       \
        unsigned c1_ = (unsigned)__shfl((int)u_[2 * f_ + 1][0], srcB);       \
        unsigned d0_ = (unsigned)__shfl((int)u_[2 * f_ + 0][1], srcB);       \
        unsigned d1_ = (unsigned)__shfl((int)u_[2 * f_ + 1][1], srcB);       \
        uint4 wv_;                                                           \
        wv_.x = qhi ? a1_ : a0_;                                             \
        wv_.y = qhi ? b1_ : b0_;                                             \
        wv_.z = qhi ? c1_ : c0_;                                             \
        wv_.w = qhi ? d1_ : d0_;                                             \
        pa_[f_] = __builtin_bit_cast(short8, wv_);                           \
      }                                                                      \
      __builtin_amdgcn_s_setprio(1);                                         \
      _Pragma("unroll")                                                      \
      for (int nd_ = 0; nd_ < 4; nd_++) {                                    \
        O[qt_][nd_] = MFMA(pa_[0], v_[nd_][0], O[qt_][nd_]);                 \
        O[qt_][nd_] = MFMA(pa_[1], v_[nd_][1], O[qt_][nd_]);                 \
      }                                                                      \
      __builtin_amdgcn_s_setprio(0);                                         \
    }                                                                        \
  } while (0)

  short8 kfA[4][2], kfB[4][2];
  LOADK(kfA, 0);
#pragma unroll 1
  for (int kt = 0; kt < 16; kt += 2) {
    LOADK(kfB, kt + 1);
    BODY(kfA, kt);
    if (kt + 2 < 16) LOADK(kfA, kt + 2);
    BODY(kfB, kt + 1);
  }
#undef LOADK
#undef BODY

  for (int qt = 0; qt < 2; qt++) {
    float s = l[qt];
    s += __shfl_xor(s, 16);
    s += __shfl_xor(s, 32);
    for (int nd = 0; nd < 4; nd++)
      for (int r = 0; r < 4; r++) {
        float linv = 1.0f / __shfl(s, quad * 4 + r);
        int q = q0 + qt * 16 + quad * 4 + r;
        int ch = h * 64 + nd * 16 + n16;
        attnT[((size_t)b * 1024 + q) * 512 + ch] = f2bs(O[qt][nd][r] * linv);
      }
  }
}

// ---------------------------------------------------------------------------
// Kernel 4: projection GEMM + bias + residual, 64x64 tiles (r7, kept).
// ---------------------------------------------------------------------------
__global__ __launch_bounds__(256) void gemm_out(
    const short* __restrict__ Wb, const short* __restrict__ Xt,
    const float* __restrict__ bias, const float* __restrict__ resid,
    float* __restrict__ out) {
  __shared__ short As[2][2048];   // 64 rows x 32 k
  __shared__ short Bs[2][2048];
  int bx = blockIdx.x, by = blockIdx.y, bb = blockIdx.z;
  int m0 = by * 64, n0 = bx * 64;
  int t = threadIdx.x;
  int w = t >> 6, lane = t & 63, n16 = lane & 15, quad = lane >> 4;
  int wm = (w >> 1) * 32, wn = (w & 1) * 32;

  const short* Wa = Wb + (size_t)(m0 + (t >> 2)) * 512 + (t & 3) * 8;
  const short* Xa = Xt + (size_t)bb * 1024 * 512 +
                    (size_t)(n0 + (t >> 2)) * 512 + (t & 3) * 8;

#define STAGE(buf, kk)                                                \
  do {                                                                \
    glds16(Wa + (kk), &As[buf][t * 8]);                               \
    glds16(Xa + (kk), &Bs[buf][t * 8]);                               \
  } while (0)

  floatx4 acc[2][2];
  for (int i = 0; i < 2; i++)
    for (int j = 0; j < 2; j++) acc[i][j] = (floatx4){0.f, 0.f, 0.f, 0.f};

  STAGE(0, 0);
#pragma unroll 1
  for (int ks = 0; ks < 16; ks++) {
    int cur = ks & 1;
    __syncthreads();
    if (ks < 15) STAGE(cur ^ 1, (ks + 1) * 32);
    short8 a[2], b[2];
    for (int im = 0; im < 2; im++)
      a[im] = *reinterpret_cast<const short8*>(
          &As[cur][(wm + im * 16 + n16) * 32 + quad * 8]);
    for (int in = 0; in < 2; in++)
      b[in] = *reinterpret_cast<const short8*>(
          &Bs[cur][(wn + in * 16 + n16) * 32 + quad * 8]);
    for (int im = 0; im < 2; im++)
      for (int in = 0; in < 2; in++)
        acc[im][in] = MFMA(a[im], b[in], acc[im][in]);
  }
#undef STAGE

  for (int im = 0; im < 2; im++) {
    int m = m0 + wm + im * 16 + quad * 4;
    float4 bi = *reinterpret_cast<const float4*>(&bias[m]);
    for (int in = 0; in < 2; in++) {
      int nn = n0 + wn + in * 16 + n16;
      size_t idx = ((size_t)bb * 512 + m) * 1024 + nn;
      out[idx]        = acc[im][in][0] + bi.x + resid[idx];
      out[idx + 1024] = acc[im][in][1] + bi.y + resid[idx + 1024];
      out[idx + 2048] = acc[im][in][2] + bi.z + resid[idx + 2048];
      out[idx + 3072] = acc[im][in][3] + bi.w + resid[idx + 3072];
    }
  }
}

// ---------------------------------------------------------------------------
extern "C" void kernel_launch(void* const* d_in, const int* in_sizes, int n_in,
                              void* d_out, int out_size, void* d_ws, size_t ws_size,
                              hipStream_t stream) {
  const float* x     = (const float*)d_in[0];
  const float* gamma = (const float*)d_in[1];
  const float* beta  = (const float*)d_in[2];
  const float* w_in  = (const float*)d_in[3];
  const float* b_in  = (const float*)d_in[4];
  const float* w_out = (const float*)d_in[5];
  const float* b_out = (const float*)d_in[6];
  float* out = (float*)d_out;

  char* ws = (char*)d_ws;
  short* ht    = (short*)ws;                    //  8 MiB [8][1024][512]
  short* Qt    = (short*)(ws + (8u  << 20));    //  8 MiB [64][1024][64]
  short* Kt    = (short*)(ws + (16u << 20));    //  8 MiB [64][1024][64]
  short* Vn    = (short*)(ws + (24u << 20));    //  8 MiB [8][512][1024]
  short* attnT = (short*)(ws + (32u << 20));    //  8 MiB [8][1024][512]
  short* wbf1  = (short*)(ws + (40u << 20));    //  1.5 MiB
  short* wbf2  = (short*)(ws + (42u << 20));    //  0.5 MiB

  gn_cast_fused<<<1280, 256, 0, stream>>>(x, gamma, beta, ht,
                                          w_in, wbf1, w_out, wbf2);
  gemm_qkv<<<dim3(8, 12, B_), 256, 0, stream>>>(wbf1, ht, b_in, Qt, Kt, Vn);
  attn_mfma<<<512, 256, 0, stream>>>(Qt, Kt, Vn, attnT);
  gemm_out<<<dim3(16, 8, B_), 256, 0, stream>>>(wbf2, attnT, b_out, x, out);
}